// Round 2
// baseline (1169.323 us; speedup 1.0000x reference)
//
#include <hip/hip_runtime.h>
#include <cmath>

typedef __bf16 bf16;
typedef __bf16 bf16x4_t __attribute__((ext_vector_type(4)));
typedef __bf16 bf16x8_t __attribute__((ext_vector_type(8)));
typedef float f32x4 __attribute__((ext_vector_type(4)));

#define GAS __attribute__((address_space(1)))
#define LAS __attribute__((address_space(3)))

// ---------------------------------------------------------------------------
// BFP quant-dequant (group=16 along K, m_bit=8) fp32 -> bf16 (values exact).
// Each thread handles 4 consecutive floats (float4); a group of 16 = 4 lanes.
// ---------------------------------------------------------------------------
__global__ __launch_bounds__(256) void bfp_quant_f32_to_bf16(
    const float* __restrict__ x, bf16* __restrict__ y, long long n4) {
  long long t = (long long)blockIdx.x * 256 + threadIdx.x;
  if (t >= n4) return;
  const float4 v = reinterpret_cast<const float4*>(x)[t];

  float a = fmaxf(fmaxf(fabsf(v.x), fabsf(v.y)), fmaxf(fabsf(v.z), fabsf(v.w)));
  a = fmaxf(a, __shfl_xor(a, 1));
  a = fmaxf(a, __shfl_xor(a, 2));   // group max over 4 lanes = 16 elems

  float q0, q1, q2, q3;
  if (a > 0.0f) {
    // floor(log2(max(a,1e-38))): biased-exponent extract. Denormal blockmax
    // (never occurs for N(0,1) inputs) gives ex=-127 = floor(log2(1e-38)).
    int ex = (int)((__float_as_uint(a) >> 23) & 0xffu) - 127;
    float scale = ldexpf(1.0f, ex - 7);   // 2^(ex-7)
    float inv   = ldexpf(1.0f, 7 - ex);   // exact power of 2: x*inv == x/scale
    q0 = fminf(fmaxf(rintf(v.x * inv), -127.0f), 127.0f) * scale;
    q1 = fminf(fmaxf(rintf(v.y * inv), -127.0f), 127.0f) * scale;
    q2 = fminf(fmaxf(rintf(v.z * inv), -127.0f), 127.0f) * scale;
    q3 = fminf(fmaxf(rintf(v.w * inv), -127.0f), 127.0f) * scale;
  } else {
    q0 = q1 = q2 = q3 = 0.0f;
  }
  // k*2^(ex-7), |k|<=127: exactly representable in bf16 -> conversion is exact
  bf16x4_t o = { (__bf16)q0, (__bf16)q1, (__bf16)q2, (__bf16)q3 };
  reinterpret_cast<bf16x4_t*>(y)[t] = o;
}

// ---------------------------------------------------------------------------
// GEMM: C[M,N] = A[M,K] * B[N,K]^T + bias[N], bf16 in / fp32 out.
// m97 structure: 128x128 block tile, BK=32, 256 threads (4 waves, 2x2),
// each wave a 64x64 sub-tile via 4x4 grid of 16x16x32 bf16 MFMAs.
// Staging via global_load_lds width=16 (wave-uniform base + lane*16).
// ---------------------------------------------------------------------------
#define BM 128
#define BN 128
#define BK 32

__global__ __launch_bounds__(256) void gemm_bf16_bt(
    const bf16* __restrict__ A,   // [Mc,K] row-major (chunk)
    const bf16* __restrict__ B,   // [N,K] row-major (i.e. B^T of the GEMM)
    const float* __restrict__ bias,
    float* __restrict__ C,        // [Mc,N] row-major (chunk)
    int N, int K) {
  __shared__ bf16 As[BM * BK];    // 8192 B, row-major [128][32], 64 B/row
  __shared__ bf16 Bs[BN * BK];

  const int tid  = threadIdx.x;
  const int bm   = blockIdx.y;
  const int bn   = blockIdx.x;
  const int wave = tid >> 6;
  const int lane = tid & 63;
  const int wr   = wave >> 1;     // wave row (0..1) -> 64 rows of C
  const int wc   = wave & 1;      // wave col (0..1) -> 64 cols of C
  const int quad = lane >> 4;     // 0..3
  const int ln   = lane & 15;

  f32x4 acc[4][4];
#pragma unroll
  for (int i = 0; i < 4; ++i)
#pragma unroll
    for (int j = 0; j < 4; ++j)
      acc[i][j] = (f32x4){0.0f, 0.0f, 0.0f, 0.0f};

  const long long kstride = (long long)K * 2;  // bytes per row
  const char* Abase = (const char*)A + (long long)bm * BM * kstride;
  const char* Bbase = (const char*)B + (long long)bn * BN * kstride;

  for (int k0 = 0; k0 < K; k0 += BK) {
    __syncthreads();   // previous tile's compute done before overwrite
#pragma unroll
    for (int r = 0; r < 2; ++r) {
      const int o   = tid * 16 + r * 4096;  // byte offset in 8192-B tile
      const int row = o >> 6;               // 64 B per row
      const int cb  = o & 63;
      const char* ga = Abase + (long long)row * kstride + (long long)k0 * 2 + cb;
      const char* gb = Bbase + (long long)row * kstride + (long long)k0 * 2 + cb;
      __builtin_amdgcn_global_load_lds((const GAS unsigned int*)ga,
                                       (LAS unsigned int*)((char*)As + o), 16, 0, 0);
      __builtin_amdgcn_global_load_lds((const GAS unsigned int*)gb,
                                       (LAS unsigned int*)((char*)Bs + o), 16, 0, 0);
    }
    __syncthreads();   // implies s_waitcnt vmcnt(0): staging visible

    bf16x8_t af[4], bfr[4];
#pragma unroll
    for (int t = 0; t < 4; ++t) {
      // A frag: A[m = ln][k = quad*8 + j], 8 contiguous bf16 -> ds_read_b128
      af[t]  = *reinterpret_cast<const bf16x8_t*>(
                   &As[(wr * 64 + t * 16 + ln) * BK + quad * 8]);
      // B frag: B[k = quad*8 + j][n = ln] == W-row n, contiguous in K
      bfr[t] = *reinterpret_cast<const bf16x8_t*>(
                   &Bs[(wc * 64 + t * 16 + ln) * BK + quad * 8]);
    }
#pragma unroll
    for (int tm = 0; tm < 4; ++tm)
#pragma unroll
      for (int tn = 0; tn < 4; ++tn)
        acc[tm][tn] = __builtin_amdgcn_mfma_f32_16x16x32_bf16(
            af[tm], bfr[tn], acc[tm][tn], 0, 0, 0);
  }

  // Epilogue: C/D mapping col = lane&15, row = quad*4 + reg (m89-verified).
  const long long row0 = (long long)bm * BM + wr * 64;
  const int col0 = bn * BN + wc * 64;
#pragma unroll
  for (int tn = 0; tn < 4; ++tn) {
    const int col = col0 + tn * 16 + ln;
    const float bv = bias[col];
#pragma unroll
    for (int tm = 0; tm < 4; ++tm) {
      const long long row = row0 + tm * 16 + quad * 4;
#pragma unroll
      for (int r = 0; r < 4; ++r)
        C[(row + r) * (long long)N + col] = acc[tm][tn][r] + bv;
    }
  }
}

extern "C" void kernel_launch(void* const* d_in, const int* in_sizes, int n_in,
                              void* d_out, int out_size, void* d_ws, size_t ws_size,
                              hipStream_t stream) {
  const float* inp    = (const float*)d_in[0];  // [B,S,K] fp32
  const float* weight = (const float*)d_in[1];  // [N,K]   fp32
  const float* bias   = (const float*)d_in[2];  // [N]     fp32
  float* out = (float*)d_out;                   // [B,S,N] fp32

  const int N = in_sizes[2];              // 4096
  const int K = in_sizes[1] / N;          // 4096
  const int M = in_sizes[0] / K;          // 16384

  // Workspace layout (adaptive to ws_size -- previous round overflowed d_ws
  // and corrupted an adjacent input buffer across graph replays):
  //   [0, qw_bytes)            : qw [N,K] bf16  (32 MiB)
  //   [qw_bytes, ...)          : qx chunk [Mc,K] bf16, Mc = multiple of BM
  const size_t qw_bytes  = (size_t)N * K * sizeof(bf16);
  const size_t row_bytes = (size_t)K * sizeof(bf16);

  long long Mc;
  if (ws_size >= qw_bytes + (size_t)M * row_bytes) {
    Mc = M;  // everything fits: single GEMM over the full problem
  } else if (ws_size >= qw_bytes + (size_t)BM * row_bytes) {
    Mc = (long long)((ws_size - qw_bytes) / row_bytes) / BM * BM;
  } else {
    Mc = BM;  // desperate floor; requires ws_size >= 33 MiB for correctness
  }

  bf16* qw = (bf16*)d_ws;
  bf16* qx = (bf16*)((char*)d_ws + qw_bytes);

  // Quantize weight once (32 MiB bf16).
  const long long n4w = (long long)N * K / 4;
  hipLaunchKernelGGL(bfp_quant_f32_to_bf16, dim3((unsigned)((n4w + 255) / 256)),
                     dim3(256), 0, stream, weight, qw, n4w);

  // Chunk over M: quantize Mc input rows, GEMM them, repeat. Same stream =>
  // serialized; chunk i+1's quant never overlaps chunk i's GEMM reads.
  for (long long m0 = 0; m0 < M; m0 += Mc) {
    const long long rows = (M - m0 < Mc) ? (M - m0) : Mc;
    const long long n4x  = rows * K / 4;
    hipLaunchKernelGGL(bfp_quant_f32_to_bf16, dim3((unsigned)((n4x + 255) / 256)),
                       dim3(256), 0, stream,
                       inp + m0 * K, qx, n4x);
    hipLaunchKernelGGL(gemm_bf16_bt,
                       dim3(N / BN, (unsigned)(rows / BM)), dim3(256), 0, stream,
                       qx, qw, bias, out + m0 * N, N, K);
  }
}